// Round 12
// baseline (454.265 us; speedup 1.0000x reference)
//
#include <hip/hip_runtime.h>
#include <hip/hip_bf16.h>

typedef __hip_bfloat16 bf16;
typedef float          f32x4 __attribute__((ext_vector_type(4)));
typedef unsigned short u16x4 __attribute__((ext_vector_type(4)));

#define N_NODES  100000
#define EMBED    64
#define N_EDGES  3200000
#define ND       6400000
#define N_LAYERS 3

// bucketed CSR build
#define PNB  256            // number of dst buckets
#define BSZ  391            // nodes per bucket (256*391 = 100096 >= N_NODES)
#define EPB  4096           // edges per partition block (even in every block)

// packed pair: (row_in_bucket << 17) | src   (src < 2^17, row < 2^9)
#define PK(r, s)  (((unsigned)(r) << 17) | (unsigned)(s))
#define PK_R(p)   ((int)((p) >> 17))
#define PK_S(p)   ((int)((p) & 0x1FFFFu))

// flags: [1] emb_outl census (over first ND/8 u16s; threshold ND/128)

__global__ void k_flags0(int* f, int* bcnt) {
    int t = threadIdx.x;
    if (t < 16) f[t] = 0;
    bcnt[t] = 0;
}

__device__ __forceinline__ int rd_src(const int* e, int i64, int k) {
    return i64 ? e[2 * k] : e[k];
}
__device__ __forceinline__ int rd_dst(const int* e, int i64, int k) {
    return i64 ? e[2 * (N_EDGES + k)] : e[N_EDGES + k];
}
__device__ __forceinline__ int clampid(int v) {
    return (v < 0) ? 0 : ((v >= N_NODES) ? (N_NODES - 1) : v);
}

// fused: emb census (sampled, block-reduced) + coarse dst-bucket histogram.
__global__ void __launch_bounds__(256) k_scanb(const int* __restrict__ edge,
                                               const uint4* __restrict__ emb4,
                                               int i64, int* __restrict__ fl,
                                               int* __restrict__ bcnt) {
    __shared__ int h[PNB];
    __shared__ int red[256];
    int t = threadIdx.x;
    int gid = blockIdx.x * 256 + t;
    int step = gridDim.x * 256;
    h[t] = 0;
    __syncthreads();

    // emb census: first ND/8 u16s as uint4 (8 u16 each)
    int local = 0;
    const int NV_M = ND / 64;                  // 100,000 vecs
#define CEN8(v)                                                          \
    {                                                                    \
        unsigned b;                                                      \
        b = ((v).x >> 8)  & 0x7f; if (b < 0x2e || b > 0x41) local++;     \
        b = ((v).x >> 24) & 0x7f; if (b < 0x2e || b > 0x41) local++;     \
        b = ((v).y >> 8)  & 0x7f; if (b < 0x2e || b > 0x41) local++;     \
        b = ((v).y >> 24) & 0x7f; if (b < 0x2e || b > 0x41) local++;     \
        b = ((v).z >> 8)  & 0x7f; if (b < 0x2e || b > 0x41) local++;     \
        b = ((v).z >> 24) & 0x7f; if (b < 0x2e || b > 0x41) local++;     \
        b = ((v).w >> 8)  & 0x7f; if (b < 0x2e || b > 0x41) local++;     \
        b = ((v).w >> 24) & 0x7f; if (b < 0x2e || b > 0x41) local++;     \
    }
    for (int i = gid; i < NV_M; i += step) {
        uint4 v = emb4[i];
        CEN8(v);
    }
#undef CEN8

    // dst-bucket histogram (uint4 loads)
    const uint4* e4 = (const uint4*)edge;
    if (i64) {
        const int base = N_EDGES / 2;          // dst half starts at word 2*N_EDGES
        const int nv   = N_EDGES / 2;          // 2 edges per vec (x,z)
        for (int k = gid; k < nv; k += step) {
            uint4 v = e4[base + k];
            atomicAdd(&h[clampid((int)v.x) / BSZ], 1);
            atomicAdd(&h[clampid((int)v.z) / BSZ], 1);
        }
    } else {
        const int base = N_EDGES / 4;          // dst half at word N_EDGES
        const int nv   = N_EDGES / 4;          // 4 edges per vec
        for (int k = gid; k < nv; k += step) {
            uint4 v = e4[base + k];
            atomicAdd(&h[clampid((int)v.x) / BSZ], 1);
            atomicAdd(&h[clampid((int)v.y) / BSZ], 1);
            atomicAdd(&h[clampid((int)v.z) / BSZ], 1);
            atomicAdd(&h[clampid((int)v.w) / BSZ], 1);
        }
    }

    red[t] = local;
    __syncthreads();                 // also fences all LDS hist atomics
    for (int s2 = 128; s2 > 0; s2 >>= 1) {
        if (t < s2) red[t] += red[t + s2];
        __syncthreads();
    }
    if (t == 0 && red[0]) atomicAdd(&fl[1], red[0]);
    if (h[t]) atomicAdd(&bcnt[t], h[t]);
}

// ---- parallel exclusive scan of bucket counts (1 block) ----
__global__ void __launch_bounds__(256) k_bscan(const int* __restrict__ bcnt,
                                               int* __restrict__ bbase,
                                               int* __restrict__ bcur) {
    __shared__ int sb[PNB];
    int t = threadIdx.x;
    int c = bcnt[t];
    sb[t] = c;
    __syncthreads();
    for (int off = 1; off < PNB; off <<= 1) {
        int v = (t >= off) ? sb[t - off] : 0;
        __syncthreads();
        sb[t] += v;
        __syncthreads();
    }
    int ex = sb[t] - c;
    bbase[t] = ex;
    bcur[t] = ex;
    if (t == PNB - 1) bbase[PNB] = sb[t];
}

// ---- partition edges into dst-buckets, LDS counting sort per 4096-edge block.
// Emits PACKED u32 pairs (row-in-bucket | src). ----
__global__ void __launch_bounds__(256) k_part(const int* __restrict__ edge,
                                              int i64,
                                              int* __restrict__ bcur,
                                              unsigned* __restrict__ pairs) {
    __shared__ int h[PNB];
    __shared__ int excl[PNB];
    __shared__ int gbase[PNB];
    __shared__ int lcur[PNB];
    __shared__ unsigned st[EPB];
    __shared__ unsigned char binof[EPB];
    int t = threadIdx.x;
    int e0 = blockIdx.x * EPB;
    int nval = N_EDGES - e0;
    if (nval > EPB) nval = EPB;
    const uint4* e4 = (const uint4*)edge;

    h[t] = 0;
    __syncthreads();
    // count pass
    if (i64) {
        int half = nval >> 1;                       // nval always even
        for (int m = t; m < half; m += 256) {
            uint4 v = e4[(size_t)(N_EDGES / 2) + (e0 >> 1) + m];
            atomicAdd(&h[clampid((int)v.x) / BSZ], 1);
            atomicAdd(&h[clampid((int)v.z) / BSZ], 1);
        }
    } else {
        for (int k = t; k < nval; k += 256) {
            int d = clampid(rd_dst(edge, 0, e0 + k));
            atomicAdd(&h[d / BSZ], 1);
        }
    }
    __syncthreads();
    int c = h[t];
    excl[t] = c;
    __syncthreads();
    for (int off = 1; off < 256; off <<= 1) {
        int v = (t >= off) ? excl[t - off] : 0;
        __syncthreads();
        excl[t] += v;
        __syncthreads();
    }
    int myexcl = excl[t] - c;
    __syncthreads();
    excl[t] = myexcl;
    gbase[t] = (c > 0) ? atomicAdd(&bcur[t], c) : 0;
    lcur[t] = myexcl;
    __syncthreads();
    // scatter into LDS, ordered by bucket
    if (i64) {
        int half = nval >> 1;
        for (int m = t; m < half; m += 256) {
            uint4 vs = e4[(e0 >> 1) + m];
            uint4 vd = e4[(size_t)(N_EDGES / 2) + (e0 >> 1) + m];
            int s0 = clampid((int)vs.x), d0 = clampid((int)vd.x);
            int b0 = d0 / BSZ;
            int lp0 = atomicAdd(&lcur[b0], 1);
            st[lp0] = PK(d0 - b0 * BSZ, s0);
            binof[lp0] = (unsigned char)b0;
            int s1 = clampid((int)vs.z), d1 = clampid((int)vd.z);
            int b1 = d1 / BSZ;
            int lp1 = atomicAdd(&lcur[b1], 1);
            st[lp1] = PK(d1 - b1 * BSZ, s1);
            binof[lp1] = (unsigned char)b1;
        }
    } else {
        for (int k = t; k < nval; k += 256) {
            int s = clampid(rd_src(edge, 0, e0 + k));
            int d = clampid(rd_dst(edge, 0, e0 + k));
            int b = d / BSZ;
            int lp = atomicAdd(&lcur[b], 1);
            st[lp] = PK(d - b * BSZ, s);
            binof[lp] = (unsigned char)b;
        }
    }
    __syncthreads();
    // flush: runs of same-bucket pairs -> contiguous global spans (coalesced)
    for (int k = t; k < nval; k += 256) {
        int b = binof[k];
        pairs[gbase[b] + (k - excl[b])] = st[k];
    }
}

// ---- fused: per-row hist -> scan -> rowptr/dis emit -> place -> init.
// One block per bucket; after CSR placement the block also converts its own
// 391 emb rows to Y0 (and out on the bf16 path) — the former k_init, whose
// stream traffic now overlaps this kernel's barrier-bound phases. ----
__global__ void __launch_bounds__(1024) k_build(const unsigned* __restrict__ pairs,
                                                const int* __restrict__ bbase,
                                                int* __restrict__ rowptr,
                                                float* __restrict__ dis,
                                                int* __restrict__ csr,
                                                const void* __restrict__ emb,
                                                const int* __restrict__ fl,
                                                float* __restrict__ out,
                                                bf16* __restrict__ Y) {
    __shared__ int hh[BSZ];     // per-row counts -> global cursors
    __shared__ int rt[512];     // row-total scan
    int b = blockIdx.x;
    int t = threadIdx.x;
    int base = b * BSZ;
    for (int i = t; i < BSZ; i += 1024) hh[i] = 0;
    __syncthreads();
    int beg = bbase[b], end = bbase[b + 1];
    for (int i = beg + t; i < end; i += 1024)
        atomicAdd(&hh[PK_R(pairs[i])], 1);
    __syncthreads();
    int rtot = (t < BSZ) ? hh[t] : 0;
    if (t < 512) rt[t] = (t < BSZ) ? rtot : 0;
    __syncthreads();
    for (int off = 1; off < 512; off <<= 1) {
        int v = 0;
        if (t < 512 && t >= off) v = rt[t - off];
        __syncthreads();
        if (t < 512 && t >= off) rt[t] += v;
        __syncthreads();
    }
    if (t < BSZ) {
        int gb = beg + (rt[t] - rtot);   // global row start
        int n = base + t;
        if (n < N_NODES) {
            dis[n] = (rtot > 0) ? rsqrtf((float)rtot) : 0.0f;
            rowptr[n] = gb;
            if (n == N_NODES - 1) rowptr[N_NODES] = N_EDGES;
        }
        hh[t] = gb;                       // -> global cursor
    }
    __syncthreads();
    for (int i = beg + t; i < end; i += 1024) {
        unsigned p = pairs[i];
        int pos = atomicAdd(&hh[PK_R(p)], 1);
        csr[pos] = PK_S(p);
    }
    // ---- fused init for this bucket's rows (dis written above is L1-hot;
    // __syncthreads already ordered the global dis writes for this block) ----
    int nrows = N_NODES - base;
    if (nrows > BSZ) nrows = BSZ;
    if (nrows <= 0) return;
    int f32path = (fl[1] >= (ND / 128));
    for (int i = t; i < nrows * 8; i += 1024) {
        int r = i >> 3, g = i & 7;
        int n = base + r;
        size_t idx = (size_t)n * 8 + g;          // 8-elem group index
        float dn = dis[n];
        float f[8];
        if (f32path) {
            const f32x4* e4 = (const f32x4*)emb + idx * 2;
            f32x4 a = e4[0], bb = e4[1];
            f[0] = a.x; f[1] = a.y; f[2] = a.z; f[3] = a.w;
            f[4] = bb.x; f[5] = bb.y; f[6] = bb.z; f[7] = bb.w;
        } else {
            const bf16* eb = (const bf16*)emb + idx * 8;
            for (int k = 0; k < 8; k++) f[k] = __bfloat162float(eb[k]);
            f32x4 oa, ob;
            oa.x = f[0]; oa.y = f[1]; oa.z = f[2]; oa.w = f[3];
            ob.x = f[4]; ob.y = f[5]; ob.z = f[6]; ob.w = f[7];
            ((f32x4*)out)[idx * 2]     = oa;
            ((f32x4*)out)[idx * 2 + 1] = ob;
        }
        u16x4 y0, y1;
        bf16 tb;
        tb = __float2bfloat16(dn * f[0]); y0.x = *(unsigned short*)&tb;
        tb = __float2bfloat16(dn * f[1]); y0.y = *(unsigned short*)&tb;
        tb = __float2bfloat16(dn * f[2]); y0.z = *(unsigned short*)&tb;
        tb = __float2bfloat16(dn * f[3]); y0.w = *(unsigned short*)&tb;
        tb = __float2bfloat16(dn * f[4]); y1.x = *(unsigned short*)&tb;
        tb = __float2bfloat16(dn * f[5]); y1.y = *(unsigned short*)&tb;
        tb = __float2bfloat16(dn * f[6]); y1.z = *(unsigned short*)&tb;
        tb = __float2bfloat16(dn * f[7]); y1.w = *(unsigned short*)&tb;
        u16x4* yp = (u16x4*)Y + idx * 2;
        yp[0] = y0;
        yp[1] = y1;
    }
}

#define GATHER4(SRC)                                                     \
    {                                                                    \
        uint2 v = *(const uint2*)(Yu + (size_t)(SRC) * 32 + l16 * 2);    \
        a0 += __uint_as_float(v.x << 16);                                \
        a1 += __uint_as_float(v.x & 0xffff0000u);                        \
        a2 += __uint_as_float(v.y << 16);                                \
        a3 += __uint_as_float(v.y & 0xffff0000u);                        \
    }

// wave-per-row whole-row SpMM (measured-fastest structure, at the empirical
// scattered-gather ceiling ~95us/layer). For the FIRST layer on the fp32
// path, the prior-accumulator stream is read from emb directly (fl-gated).
__global__ void __launch_bounds__(256) k_spmm(
        const int* __restrict__ rowptr, const int* __restrict__ csr,
        const float* __restrict__ dis, const bf16* __restrict__ Yin,
        const float* __restrict__ emb, const int* __restrict__ fl,
        float* __restrict__ out, bf16* __restrict__ Yout, int first, int last) {
    int wave = threadIdx.x >> 6;
    int lane = threadIdx.x & 63;
    int q    = lane >> 4;        // edge quarter
    int l16  = lane & 15;        // col group: cols 4*l16 .. 4*l16+3
    int n = blockIdx.x * 4 + wave;
    if (n >= N_NODES) return;
    int beg = rowptr[n];
    int end = rowptr[n + 1];
    const unsigned* Yu = (const unsigned*)Yin;   // 2 bf16 per word
    float a0 = 0.f, a1 = 0.f, a2 = 0.f, a3 = 0.f;
    int j = beg;
    for (; j + 16 <= end; j += 16) {
        int s0 = csr[j + q];
        int s1 = csr[j + 4 + q];
        int s2 = csr[j + 8 + q];
        int s3 = csr[j + 12 + q];
        GATHER4(s0);
        GATHER4(s1);
        GATHER4(s2);
        GATHER4(s3);
    }
    for (; j + 8 <= end; j += 8) {
        int s0 = csr[j + q];
        int s1 = csr[j + 4 + q];
        GATHER4(s0);
        GATHER4(s1);
    }
    if (j + q < end)     { int sv = csr[j + q];     GATHER4(sv); }
    if (j + 4 + q < end) { int sv = csr[j + 4 + q]; GATHER4(sv); }
    // combine the 4 quarters: lanes l, l^16, l^32, l^48 hold the same cols
    a0 += __shfl_xor(a0, 16); a0 += __shfl_xor(a0, 32);
    a1 += __shfl_xor(a1, 16); a1 += __shfl_xor(a1, 32);
    a2 += __shfl_xor(a2, 16); a2 += __shfl_xor(a2, 32);
    a3 += __shfl_xor(a3, 16); a3 += __shfl_xor(a3, 32);
    if (lane < 16) {
        float dn = dis[n];
        float x0 = dn * a0, x1 = dn * a1, x2 = dn * a2, x3 = dn * a3;
        int i4 = n * 16 + l16;                 // f32x4 index
        const f32x4* ip = (first && fl[1] >= (ND / 128))
                              ? (const f32x4*)emb : (const f32x4*)out;
        f32x4 o = __builtin_nontemporal_load(ip + i4);
        if (last) {
            o.x = (o.x + x0) * 0.25f;
            o.y = (o.y + x1) * 0.25f;
            o.z = (o.z + x2) * 0.25f;
            o.w = (o.w + x3) * 0.25f;
            __builtin_nontemporal_store(o, (f32x4*)out + i4);
        } else {
            o.x += x0; o.y += x1; o.z += x2; o.w += x3;
            __builtin_nontemporal_store(o, (f32x4*)out + i4);
            bf16 t0 = __float2bfloat16(dn * x0);
            bf16 t1 = __float2bfloat16(dn * x1);
            bf16 t2 = __float2bfloat16(dn * x2);
            bf16 t3 = __float2bfloat16(dn * x3);
            u16x4 yv;
            yv.x = *(unsigned short*)&t0;
            yv.y = *(unsigned short*)&t1;
            yv.z = *(unsigned short*)&t2;
            yv.w = *(unsigned short*)&t3;
            __builtin_nontemporal_store(yv, (u16x4*)Yout + (size_t)n * 16 + l16);
        }
    }
}

__global__ void k_fill42(float* __restrict__ o) {
    int i = blockIdx.x * blockDim.x + threadIdx.x;
    if (i < ND) o[i] = 42.0f;   // signature: ws too small for CSR layout
}

extern "C" void kernel_launch(void* const* d_in, const int* in_sizes, int n_in,
                              void* d_out, int out_size, void* d_ws, size_t ws_size,
                              hipStream_t stream) {
    const void* emb = d_in[0];
    const int* edge = (const int*)d_in[1];
    float* out = (float*)d_out;

    // host-side dtype resolution: int64 edge buffer = 2*E*8 bytes
    const long long i64_bytes = 2LL * N_EDGES * 8;
    int i64 = (in_sizes[1] >= (int)i64_bytes) ? 1 : 0;

    const int B = 256;
    const int gND = (ND + B - 1) / B;           // 25000
    const int gP  = (N_EDGES + EPB - 1) / EPB;  // 782 partition blocks
    const int gW  = (N_NODES + 3) / 4;          // 25000 wave-per-row blocks

    char* ws = (char*)d_ws;
    int* fl = (int*)ws;
    size_t off = 256;
    const size_t off_dis    = off;  off += (size_t)N_NODES * 4;
    const size_t off_rowptr = off;  off += (size_t)(N_NODES + 1) * 4 + 4;
    const size_t off_bcnt   = off;  off += 1024;
    const size_t off_bbase  = off;  off += 1056;
    const size_t off_bcur   = off;  off += 1024;
    const size_t off_csr    = off;  off += (size_t)N_EDGES * 4;
    const size_t off_Y0     = off;  off += (size_t)ND * 2;
    const size_t off_Y1     = off;  off += (size_t)ND * 2;
    const size_t need = off;                    // ~39.2 MB

    if (ws_size < need) {
        k_fill42<<<gND, B, 0, stream>>>(out);
        return;
    }

    float*    dis    = (float*)(ws + off_dis);
    int*      rowptr = (int*)(ws + off_rowptr);
    int*      bcnt   = (int*)(ws + off_bcnt);
    int*      bbase  = (int*)(ws + off_bbase);
    int*      bcur   = (int*)(ws + off_bcur);
    int*      csr    = (int*)(ws + off_csr);
    unsigned* pairs  = (unsigned*)(ws + off_Y1); // 12.8MB packed, overlays Y1
                                                 // (dead until spmm layer 1;
                                                 //  k_build writes Y0)
    bf16*     Y0     = (bf16*)(ws + off_Y0);
    bf16*     Y1     = (bf16*)(ws + off_Y1);

    k_flags0<<<1, 256, 0, stream>>>(fl, bcnt);
    k_scanb<<<1024, B, 0, stream>>>(edge, (const uint4*)emb, i64, fl, bcnt);

    // bucketed CSR build (packed pairs) + fused init
    k_bscan<<<1, 256, 0, stream>>>(bcnt, bbase, bcur);
    k_part<<<gP, B, 0, stream>>>(edge, i64, bcur, pairs);
    k_build<<<PNB, 1024, 0, stream>>>(pairs, bbase, rowptr, dis, csr,
                                      emb, fl, out, Y0);

    k_spmm<<<gW, B, 0, stream>>>(rowptr, csr, dis, Y0, (const float*)emb, fl, out, Y1, 1, 0);
    k_spmm<<<gW, B, 0, stream>>>(rowptr, csr, dis, Y1, (const float*)emb, fl, out, Y0, 0, 0);
    k_spmm<<<gW, B, 0, stream>>>(rowptr, csr, dis, Y0, (const float*)emb, fl, out, Y1, 0, 1);
}

// Round 13
// 445.236 us; speedup vs baseline: 1.0203x; 1.0203x over previous
//
#include <hip/hip_runtime.h>
#include <hip/hip_bf16.h>

typedef __hip_bfloat16 bf16;
typedef float          f32x4 __attribute__((ext_vector_type(4)));
typedef unsigned short u16x4 __attribute__((ext_vector_type(4)));

#define N_NODES  100000
#define EMBED    64
#define N_EDGES  3200000
#define ND       6400000
#define N_LAYERS 3

// bucketed CSR build
#define PNB  256            // number of dst buckets
#define BSZ  391            // nodes per bucket (256*391 = 100096 >= N_NODES)
#define EPB  4096           // edges per partition block (even in every block)

// packed pair: (row_in_bucket << 17) | src   (src < 2^17, row < 2^9)
#define PK(r, s)  (((unsigned)(r) << 17) | (unsigned)(s))
#define PK_R(p)   ((int)((p) >> 17))
#define PK_S(p)   ((int)((p) & 0x1FFFFu))

// flags: [1] emb_outl census (over first ND/8 u16s; threshold ND/128)

__global__ void k_flags0(int* f, int* bcnt) {
    int t = threadIdx.x;
    if (t < 16) f[t] = 0;
    bcnt[t] = 0;
}

__device__ __forceinline__ int rd_src(const int* e, int i64, int k) {
    return i64 ? e[2 * k] : e[k];
}
__device__ __forceinline__ int rd_dst(const int* e, int i64, int k) {
    return i64 ? e[2 * (N_EDGES + k)] : e[N_EDGES + k];
}
__device__ __forceinline__ int clampid(int v) {
    return (v < 0) ? 0 : ((v >= N_NODES) ? (N_NODES - 1) : v);
}

// fused: emb census (sampled, block-reduced) + coarse dst-bucket histogram.
__global__ void __launch_bounds__(256) k_scanb(const int* __restrict__ edge,
                                               const uint4* __restrict__ emb4,
                                               int i64, int* __restrict__ fl,
                                               int* __restrict__ bcnt) {
    __shared__ int h[PNB];
    __shared__ int red[256];
    int t = threadIdx.x;
    int gid = blockIdx.x * 256 + t;
    int step = gridDim.x * 256;
    h[t] = 0;
    __syncthreads();

    // emb census: first ND/8 u16s as uint4 (8 u16 each)
    int local = 0;
    const int NV_M = ND / 64;                  // 100,000 vecs
#define CEN8(v)                                                          \
    {                                                                    \
        unsigned b;                                                      \
        b = ((v).x >> 8)  & 0x7f; if (b < 0x2e || b > 0x41) local++;     \
        b = ((v).x >> 24) & 0x7f; if (b < 0x2e || b > 0x41) local++;     \
        b = ((v).y >> 8)  & 0x7f; if (b < 0x2e || b > 0x41) local++;     \
        b = ((v).y >> 24) & 0x7f; if (b < 0x2e || b > 0x41) local++;     \
        b = ((v).z >> 8)  & 0x7f; if (b < 0x2e || b > 0x41) local++;     \
        b = ((v).z >> 24) & 0x7f; if (b < 0x2e || b > 0x41) local++;     \
        b = ((v).w >> 8)  & 0x7f; if (b < 0x2e || b > 0x41) local++;     \
        b = ((v).w >> 24) & 0x7f; if (b < 0x2e || b > 0x41) local++;     \
    }
    for (int i = gid; i < NV_M; i += step) {
        uint4 v = emb4[i];
        CEN8(v);
    }
#undef CEN8

    // dst-bucket histogram (uint4 loads)
    const uint4* e4 = (const uint4*)edge;
    if (i64) {
        const int base = N_EDGES / 2;          // dst half starts at word 2*N_EDGES
        const int nv   = N_EDGES / 2;          // 2 edges per vec (x,z)
        for (int k = gid; k < nv; k += step) {
            uint4 v = e4[base + k];
            atomicAdd(&h[clampid((int)v.x) / BSZ], 1);
            atomicAdd(&h[clampid((int)v.z) / BSZ], 1);
        }
    } else {
        const int base = N_EDGES / 4;          // dst half at word N_EDGES
        const int nv   = N_EDGES / 4;          // 4 edges per vec
        for (int k = gid; k < nv; k += step) {
            uint4 v = e4[base + k];
            atomicAdd(&h[clampid((int)v.x) / BSZ], 1);
            atomicAdd(&h[clampid((int)v.y) / BSZ], 1);
            atomicAdd(&h[clampid((int)v.z) / BSZ], 1);
            atomicAdd(&h[clampid((int)v.w) / BSZ], 1);
        }
    }

    red[t] = local;
    __syncthreads();                 // also fences all LDS hist atomics
    for (int s2 = 128; s2 > 0; s2 >>= 1) {
        if (t < s2) red[t] += red[t + s2];
        __syncthreads();
    }
    if (t == 0 && red[0]) atomicAdd(&fl[1], red[0]);
    if (h[t]) atomicAdd(&bcnt[t], h[t]);
}

// ---- parallel exclusive scan of bucket counts (1 block) ----
__global__ void __launch_bounds__(256) k_bscan(const int* __restrict__ bcnt,
                                               int* __restrict__ bbase,
                                               int* __restrict__ bcur) {
    __shared__ int sb[PNB];
    int t = threadIdx.x;
    int c = bcnt[t];
    sb[t] = c;
    __syncthreads();
    for (int off = 1; off < PNB; off <<= 1) {
        int v = (t >= off) ? sb[t - off] : 0;
        __syncthreads();
        sb[t] += v;
        __syncthreads();
    }
    int ex = sb[t] - c;
    bbase[t] = ex;
    bcur[t] = ex;
    if (t == PNB - 1) bbase[PNB] = sb[t];
}

// ---- partition edges into dst-buckets, LDS counting sort per 4096-edge block.
// Emits PACKED u32 pairs (row-in-bucket | src). LDS 24KB. ----
__global__ void __launch_bounds__(256) k_part(const int* __restrict__ edge,
                                              int i64,
                                              int* __restrict__ bcur,
                                              unsigned* __restrict__ pairs) {
    __shared__ int h[PNB];
    __shared__ int excl[PNB];
    __shared__ int gbase[PNB];
    __shared__ int lcur[PNB];
    __shared__ unsigned st[EPB];
    __shared__ unsigned char binof[EPB];
    int t = threadIdx.x;
    int e0 = blockIdx.x * EPB;
    int nval = N_EDGES - e0;
    if (nval > EPB) nval = EPB;
    const uint4* e4 = (const uint4*)edge;

    h[t] = 0;
    __syncthreads();
    // count pass
    if (i64) {
        int half = nval >> 1;                       // nval always even
        for (int m = t; m < half; m += 256) {
            uint4 v = e4[(size_t)(N_EDGES / 2) + (e0 >> 1) + m];
            atomicAdd(&h[clampid((int)v.x) / BSZ], 1);
            atomicAdd(&h[clampid((int)v.z) / BSZ], 1);
        }
    } else {
        for (int k = t; k < nval; k += 256) {
            int d = clampid(rd_dst(edge, 0, e0 + k));
            atomicAdd(&h[d / BSZ], 1);
        }
    }
    __syncthreads();
    int c = h[t];
    excl[t] = c;
    __syncthreads();
    for (int off = 1; off < 256; off <<= 1) {
        int v = (t >= off) ? excl[t - off] : 0;
        __syncthreads();
        excl[t] += v;
        __syncthreads();
    }
    int myexcl = excl[t] - c;
    __syncthreads();
    excl[t] = myexcl;
    gbase[t] = (c > 0) ? atomicAdd(&bcur[t], c) : 0;
    lcur[t] = myexcl;
    __syncthreads();
    // scatter into LDS, ordered by bucket
    if (i64) {
        int half = nval >> 1;
        for (int m = t; m < half; m += 256) {
            uint4 vs = e4[(e0 >> 1) + m];
            uint4 vd = e4[(size_t)(N_EDGES / 2) + (e0 >> 1) + m];
            int s0 = clampid((int)vs.x), d0 = clampid((int)vd.x);
            int b0 = d0 / BSZ;
            int lp0 = atomicAdd(&lcur[b0], 1);
            st[lp0] = PK(d0 - b0 * BSZ, s0);
            binof[lp0] = (unsigned char)b0;
            int s1 = clampid((int)vs.z), d1 = clampid((int)vd.z);
            int b1 = d1 / BSZ;
            int lp1 = atomicAdd(&lcur[b1], 1);
            st[lp1] = PK(d1 - b1 * BSZ, s1);
            binof[lp1] = (unsigned char)b1;
        }
    } else {
        for (int k = t; k < nval; k += 256) {
            int s = clampid(rd_src(edge, 0, e0 + k));
            int d = clampid(rd_dst(edge, 0, e0 + k));
            int b = d / BSZ;
            int lp = atomicAdd(&lcur[b], 1);
            st[lp] = PK(d - b * BSZ, s);
            binof[lp] = (unsigned char)b;
        }
    }
    __syncthreads();
    // flush: runs of same-bucket pairs -> contiguous global spans (coalesced)
    for (int k = t; k < nval; k += 256) {
        int b = binof[k];
        pairs[gbase[b] + (k - excl[b])] = st[k];
    }
}

// ---- fused: per-row hist -> scan -> rowptr/dis emit -> place (packed pairs) ----
__global__ void __launch_bounds__(1024) k_build(const unsigned* __restrict__ pairs,
                                                const int* __restrict__ bbase,
                                                int* __restrict__ rowptr,
                                                float* __restrict__ dis,
                                                int* __restrict__ csr) {
    __shared__ int hh[BSZ];     // per-row counts -> global cursors
    __shared__ int rt[512];     // row-total scan
    int b = blockIdx.x;
    int t = threadIdx.x;
    int base = b * BSZ;
    for (int i = t; i < BSZ; i += 1024) hh[i] = 0;
    __syncthreads();
    int beg = bbase[b], end = bbase[b + 1];
    for (int i = beg + t; i < end; i += 1024)
        atomicAdd(&hh[PK_R(pairs[i])], 1);
    __syncthreads();
    int rtot = (t < BSZ) ? hh[t] : 0;
    if (t < 512) rt[t] = (t < BSZ) ? rtot : 0;
    __syncthreads();
    for (int off = 1; off < 512; off <<= 1) {
        int v = 0;
        if (t < 512 && t >= off) v = rt[t - off];
        __syncthreads();
        if (t < 512 && t >= off) rt[t] += v;
        __syncthreads();
    }
    if (t < BSZ) {
        int gb = beg + (rt[t] - rtot);   // global row start
        int n = base + t;
        if (n < N_NODES) {
            dis[n] = (rtot > 0) ? rsqrtf((float)rtot) : 0.0f;
            rowptr[n] = gb;
            if (n == N_NODES - 1) rowptr[N_NODES] = N_EDGES;
        }
        hh[t] = gb;                       // -> global cursor
    }
    __syncthreads();
    for (int i = beg + t; i < end; i += 1024) {
        unsigned p = pairs[i];
        int pos = atomicAdd(&hh[PK_R(p)], 1);
        csr[pos] = PK_S(p);
    }
}

// Y0 = bf16(dis ⊙ emb), ROW-MAJOR. On the fp32 path `out` is NOT written
// (first spmm reads emb directly); on the bf16 path out = emb (decoded).
__global__ void __launch_bounds__(256) k_init(const void* __restrict__ emb,
                                              const int* __restrict__ fl,
                                              const float* __restrict__ dis,
                                              float* __restrict__ out,
                                              bf16* __restrict__ Y) {
    int idx = blockIdx.x * 256 + threadIdx.x;      // 800K threads
    if (idx >= ND / 8) return;
    int n = idx >> 3;
    float dn = dis[n];
    float f[8];
    if (fl[1] < (ND / 128)) {                      // bf16 emb (sampled census)
        const bf16* eb = (const bf16*)emb + (size_t)idx * 8;
        for (int k = 0; k < 8; k++) f[k] = __bfloat162float(eb[k]);
        f32x4* o4 = (f32x4*)out + (size_t)idx * 2;
        f32x4 oa, ob;
        oa.x = f[0]; oa.y = f[1]; oa.z = f[2]; oa.w = f[3];
        ob.x = f[4]; ob.y = f[5]; ob.z = f[6]; ob.w = f[7];
        o4[0] = oa; o4[1] = ob;
    } else {
        const f32x4* e4 = (const f32x4*)emb + (size_t)idx * 2;
        f32x4 a = e4[0], b = e4[1];
        f[0] = a.x; f[1] = a.y; f[2] = a.z; f[3] = a.w;
        f[4] = b.x; f[5] = b.y; f[6] = b.z; f[7] = b.w;
    }
    u16x4* yp = (u16x4*)Y + (size_t)idx * 2;
    u16x4 y0, y1;
    bf16 tb;
    tb = __float2bfloat16(dn * f[0]); y0.x = *(unsigned short*)&tb;
    tb = __float2bfloat16(dn * f[1]); y0.y = *(unsigned short*)&tb;
    tb = __float2bfloat16(dn * f[2]); y0.z = *(unsigned short*)&tb;
    tb = __float2bfloat16(dn * f[3]); y0.w = *(unsigned short*)&tb;
    tb = __float2bfloat16(dn * f[4]); y1.x = *(unsigned short*)&tb;
    tb = __float2bfloat16(dn * f[5]); y1.y = *(unsigned short*)&tb;
    tb = __float2bfloat16(dn * f[6]); y1.z = *(unsigned short*)&tb;
    tb = __float2bfloat16(dn * f[7]); y1.w = *(unsigned short*)&tb;
    yp[0] = y0; yp[1] = y1;
}

#define GATHER4(SRC)                                                     \
    {                                                                    \
        uint2 v = *(const uint2*)(Yu + (size_t)(SRC) * 32 + l16 * 2);    \
        a0 += __uint_as_float(v.x << 16);                                \
        a1 += __uint_as_float(v.x & 0xffff0000u);                        \
        a2 += __uint_as_float(v.y << 16);                                \
        a3 += __uint_as_float(v.y & 0xffff0000u);                        \
    }

// wave-per-row whole-row SpMM (measured-fastest structure, at the empirical
// scattered-gather ceiling ~95us/layer). For the FIRST layer on the fp32
// path, the prior-accumulator stream is read from emb directly (fl-gated).
__global__ void __launch_bounds__(256) k_spmm(
        const int* __restrict__ rowptr, const int* __restrict__ csr,
        const float* __restrict__ dis, const bf16* __restrict__ Yin,
        const float* __restrict__ emb, const int* __restrict__ fl,
        float* __restrict__ out, bf16* __restrict__ Yout, int first, int last) {
    int wave = threadIdx.x >> 6;
    int lane = threadIdx.x & 63;
    int q    = lane >> 4;        // edge quarter
    int l16  = lane & 15;        // col group: cols 4*l16 .. 4*l16+3
    int n = blockIdx.x * 4 + wave;
    if (n >= N_NODES) return;
    int beg = rowptr[n];
    int end = rowptr[n + 1];
    const unsigned* Yu = (const unsigned*)Yin;   // 2 bf16 per word
    float a0 = 0.f, a1 = 0.f, a2 = 0.f, a3 = 0.f;
    int j = beg;
    for (; j + 16 <= end; j += 16) {
        int s0 = csr[j + q];
        int s1 = csr[j + 4 + q];
        int s2 = csr[j + 8 + q];
        int s3 = csr[j + 12 + q];
        GATHER4(s0);
        GATHER4(s1);
        GATHER4(s2);
        GATHER4(s3);
    }
    for (; j + 8 <= end; j += 8) {
        int s0 = csr[j + q];
        int s1 = csr[j + 4 + q];
        GATHER4(s0);
        GATHER4(s1);
    }
    if (j + q < end)     { int sv = csr[j + q];     GATHER4(sv); }
    if (j + 4 + q < end) { int sv = csr[j + 4 + q]; GATHER4(sv); }
    // combine the 4 quarters: lanes l, l^16, l^32, l^48 hold the same cols
    a0 += __shfl_xor(a0, 16); a0 += __shfl_xor(a0, 32);
    a1 += __shfl_xor(a1, 16); a1 += __shfl_xor(a1, 32);
    a2 += __shfl_xor(a2, 16); a2 += __shfl_xor(a2, 32);
    a3 += __shfl_xor(a3, 16); a3 += __shfl_xor(a3, 32);
    if (lane < 16) {
        float dn = dis[n];
        float x0 = dn * a0, x1 = dn * a1, x2 = dn * a2, x3 = dn * a3;
        int i4 = n * 16 + l16;                 // f32x4 index
        const f32x4* ip = (first && fl[1] >= (ND / 128))
                              ? (const f32x4*)emb : (const f32x4*)out;
        f32x4 o = __builtin_nontemporal_load(ip + i4);
        if (last) {
            o.x = (o.x + x0) * 0.25f;
            o.y = (o.y + x1) * 0.25f;
            o.z = (o.z + x2) * 0.25f;
            o.w = (o.w + x3) * 0.25f;
            __builtin_nontemporal_store(o, (f32x4*)out + i4);
        } else {
            o.x += x0; o.y += x1; o.z += x2; o.w += x3;
            __builtin_nontemporal_store(o, (f32x4*)out + i4);
            bf16 t0 = __float2bfloat16(dn * x0);
            bf16 t1 = __float2bfloat16(dn * x1);
            bf16 t2 = __float2bfloat16(dn * x2);
            bf16 t3 = __float2bfloat16(dn * x3);
            u16x4 yv;
            yv.x = *(unsigned short*)&t0;
            yv.y = *(unsigned short*)&t1;
            yv.z = *(unsigned short*)&t2;
            yv.w = *(unsigned short*)&t3;
            __builtin_nontemporal_store(yv, (u16x4*)Yout + (size_t)n * 16 + l16);
        }
    }
}

__global__ void k_fill42(float* __restrict__ o) {
    int i = blockIdx.x * blockDim.x + threadIdx.x;
    if (i < ND) o[i] = 42.0f;   // signature: ws too small for CSR layout
}

extern "C" void kernel_launch(void* const* d_in, const int* in_sizes, int n_in,
                              void* d_out, int out_size, void* d_ws, size_t ws_size,
                              hipStream_t stream) {
    const void* emb = d_in[0];
    const int* edge = (const int*)d_in[1];
    float* out = (float*)d_out;

    // host-side dtype resolution: int64 edge buffer = 2*E*8 bytes
    const long long i64_bytes = 2LL * N_EDGES * 8;
    int i64 = (in_sizes[1] >= (int)i64_bytes) ? 1 : 0;

    const int B = 256;
    const int gND = (ND + B - 1) / B;           // 25000
    const int gI  = (ND / 8 + B - 1) / B;       // 3125
    const int gP  = (N_EDGES + EPB - 1) / EPB;  // 782 partition blocks
    const int gW  = (N_NODES + 3) / 4;          // 25000 wave-per-row blocks

    char* ws = (char*)d_ws;
    int* fl = (int*)ws;
    size_t off = 256;
    const size_t off_dis    = off;  off += (size_t)N_NODES * 4;
    const size_t off_rowptr = off;  off += (size_t)(N_NODES + 1) * 4 + 4;
    const size_t off_bcnt   = off;  off += 1024;
    const size_t off_bbase  = off;  off += 1056;
    const size_t off_bcur   = off;  off += 1024;
    const size_t off_csr    = off;  off += (size_t)N_EDGES * 4;
    const size_t off_Y0     = off;  off += (size_t)ND * 2;
    const size_t off_Y1     = off;  off += (size_t)ND * 2;
    const size_t need = off;                    // ~39.2 MB

    if (ws_size < need) {
        k_fill42<<<gND, B, 0, stream>>>(out);
        return;
    }

    float*    dis    = (float*)(ws + off_dis);
    int*      rowptr = (int*)(ws + off_rowptr);
    int*      bcnt   = (int*)(ws + off_bcnt);
    int*      bbase  = (int*)(ws + off_bbase);
    int*      bcur   = (int*)(ws + off_bcur);
    int*      csr    = (int*)(ws + off_csr);
    unsigned* pairs  = (unsigned*)(ws + off_Y0); // 12.8MB packed, reuses Y0 (dead until k_init)
    bf16*     Y0     = (bf16*)(ws + off_Y0);
    bf16*     Y1     = (bf16*)(ws + off_Y1);

    k_flags0<<<1, 256, 0, stream>>>(fl, bcnt);
    k_scanb<<<512, B, 0, stream>>>(edge, (const uint4*)emb, i64, fl, bcnt);

    // bucketed CSR build (packed pairs)
    k_bscan<<<1, 256, 0, stream>>>(bcnt, bbase, bcur);
    k_part<<<gP, B, 0, stream>>>(edge, i64, bcur, pairs);
    k_build<<<PNB, 1024, 0, stream>>>(pairs, bbase, rowptr, dis, csr);

    k_init<<<gI, B, 0, stream>>>(emb, fl, dis, out, Y0);

    k_spmm<<<gW, B, 0, stream>>>(rowptr, csr, dis, Y0, (const float*)emb, fl, out, Y1, 1, 0);
    k_spmm<<<gW, B, 0, stream>>>(rowptr, csr, dis, Y1, (const float*)emb, fl, out, Y0, 0, 0);
    k_spmm<<<gW, B, 0, stream>>>(rowptr, csr, dis, Y0, (const float*)emb, fl, out, Y1, 0, 1);
}